// Round 1
// baseline (120.215 us; speedup 1.0000x reference)
//
#include <hip/hip_runtime.h>

// QuantumPINN: out = a*z + b, z = <psi| Z |psi>, psi = U(weights) RY(x)|0>.
// Algebraic collapse: out = K0 + K1*cos(x) + K2*sin(x)
//                         = K0 + R*cos(x - phi),  R = sqrt(K1^2+K2^2), phi = atan2(K2,K1).
// Split launch: 1-thread coeff kernel -> d_ws{K0, R, -phi/2pi}; then a pure
// streaming kernel: per element fma -> v_cos_f32 (revolutions) -> fma.

struct cplx { float re, im; };

__device__ inline cplx cmul(cplx p, cplx q) {
    return cplx{p.re * q.re - p.im * q.im, p.re * q.im + p.im * q.re};
}
__device__ inline cplx cadd(cplx p, cplx q) { return cplx{p.re + q.re, p.im + q.im}; }

// Coefficients from the 6 weights. Accurate sincosf: one thread, cost irrelevant.
__device__ inline void qpinn_coeffs(const float* __restrict__ w, float a, float b,
                                    float& K0, float& R, float& mphirev) {
    cplx U00{1.f, 0.f}, U01{0.f, 0.f}, U10{0.f, 0.f}, U11{1.f, 0.f};
    #pragma unroll
    for (int l = 0; l < 2; ++l) {
        const float h0 = 0.5f * w[3 * l + 0];
        const float h1 = 0.5f * w[3 * l + 1];
        const float h2 = 0.5f * w[3 * l + 2];
        float c0, s0, c1, s1, c2, s2;
        sincosf(h0, &s0, &c0);
        sincosf(h1, &s1, &c1);
        sincosf(h2, &s2, &c2);

        // RX = [[c0, -i s0], [-i s0, c0]]
        cplx X00{c0, 0.f}, X01{0.f, -s0}, X10{0.f, -s0}, X11{c0, 0.f};
        // RY = [[c1, -s1], [s1, c1]]
        cplx Y00{c1, 0.f}, Y01{-s1, 0.f}, Y10{s1, 0.f}, Y11{c1, 0.f};
        cplx A00 = cadd(cmul(Y00, X00), cmul(Y01, X10));
        cplx A01 = cadd(cmul(Y00, X01), cmul(Y01, X11));
        cplx A10 = cadd(cmul(Y10, X00), cmul(Y11, X10));
        cplx A11 = cadd(cmul(Y10, X01), cmul(Y11, X11));
        // RZ = diag(e^{-i h2}, e^{+i h2})
        cplx zm{c2, -s2}, zp{c2, s2};
        cplx L00 = cmul(zm, A00), L01 = cmul(zm, A01);
        cplx L10 = cmul(zp, A10), L11 = cmul(zp, A11);
        cplx n00 = cadd(cmul(L00, U00), cmul(L01, U10));
        cplx n01 = cadd(cmul(L00, U01), cmul(L01, U11));
        cplx n10 = cadd(cmul(L10, U00), cmul(L11, U10));
        cplx n11 = cadd(cmul(L10, U01), cmul(L11, U11));
        U00 = n00; U01 = n01; U10 = n10; U11 = n11;
    }
    const float A = (U00.re * U00.re + U00.im * U00.im) - (U10.re * U10.re + U10.im * U10.im);
    const float B = (U01.re * U01.re + U01.im * U01.im) - (U11.re * U11.re + U11.im * U11.im);
    const float C = 2.f * ((U00.re * U01.re + U00.im * U01.im) -
                           (U10.re * U11.re + U10.im * U11.im));
    K0 = fmaf(a, 0.5f * (A + B), b);
    const float K1 = a * 0.5f * (A - B);
    const float K2 = a * 0.5f * C;
    R = sqrtf(K1 * K1 + K2 * K2);
    const float INV2PI = 0.15915494309189535f;
    mphirev = -atan2f(K2, K1) * INV2PI;   // phase pre-converted to revolutions
}

__global__ void coeff_kernel(const float* __restrict__ w, const float* __restrict__ pa,
                             const float* __restrict__ pb, float* __restrict__ coef) {
    if (threadIdx.x == 0) {
        float K0, R, mphirev;
        qpinn_coeffs(w, pa[0], pb[0], K0, R, mphirev);
        coef[0] = K0; coef[1] = R; coef[2] = mphirev;
    }
}

// Pure streaming: per element t = fma(x, 1/2pi, -phi_rev); out = fma(R, cos(2pi*t), K0).
// gfx950 v_cos_f32 input is in REVOLUTIONS (cdna4_isa.md §3); |x|<~6 => |t|<1, in range.
__global__ __launch_bounds__(256) void stream_kernel(
    const float* __restrict__ x, const float* __restrict__ coef,
    float* __restrict__ out, int n4) {

    const float K0 = coef[0];
    const float R  = coef[1];
    const float mphirev = coef[2];
    const float INV2PI = 0.15915494309189535f;

    const float4* __restrict__ x4 = (const float4*)x;
    float4* __restrict__ o4 = (float4*)out;

    const int stride = gridDim.x * blockDim.x;
    for (int i = blockIdx.x * blockDim.x + threadIdx.x; i < n4; i += stride) {
        float4 v = x4[i];
        float4 r;
        r.x = fmaf(R, __builtin_amdgcn_cosf(fmaf(v.x, INV2PI, mphirev)), K0);
        r.y = fmaf(R, __builtin_amdgcn_cosf(fmaf(v.y, INV2PI, mphirev)), K0);
        r.z = fmaf(R, __builtin_amdgcn_cosf(fmaf(v.z, INV2PI, mphirev)), K0);
        r.w = fmaf(R, __builtin_amdgcn_cosf(fmaf(v.w, INV2PI, mphirev)), K0);
        o4[i] = r;
    }
}

// Fallback if the harness provides no workspace: per-thread coeffs (old behavior,
// but with the 1-trans inner loop).
__global__ __launch_bounds__(256) void fused_kernel(
    const float* __restrict__ x, const float* __restrict__ w,
    const float* __restrict__ pa, const float* __restrict__ pb,
    float* __restrict__ out, int n4) {

    float K0, R, mphirev;
    qpinn_coeffs(w, pa[0], pb[0], K0, R, mphirev);
    const float INV2PI = 0.15915494309189535f;

    const float4* __restrict__ x4 = (const float4*)x;
    float4* __restrict__ o4 = (float4*)out;

    const int stride = gridDim.x * blockDim.x;
    for (int i = blockIdx.x * blockDim.x + threadIdx.x; i < n4; i += stride) {
        float4 v = x4[i];
        float4 r;
        r.x = fmaf(R, __builtin_amdgcn_cosf(fmaf(v.x, INV2PI, mphirev)), K0);
        r.y = fmaf(R, __builtin_amdgcn_cosf(fmaf(v.y, INV2PI, mphirev)), K0);
        r.z = fmaf(R, __builtin_amdgcn_cosf(fmaf(v.z, INV2PI, mphirev)), K0);
        r.w = fmaf(R, __builtin_amdgcn_cosf(fmaf(v.w, INV2PI, mphirev)), K0);
        o4[i] = r;
    }
}

extern "C" void kernel_launch(void* const* d_in, const int* in_sizes, int n_in,
                              void* d_out, int out_size, void* d_ws, size_t ws_size,
                              hipStream_t stream) {
    const float* x = (const float*)d_in[0];
    const float* w = (const float*)d_in[1];   // [L=2, 3]
    const float* a = (const float*)d_in[2];
    const float* b = (const float*)d_in[3];
    float* out = (float*)d_out;

    const int n = in_sizes[0];       // 16777216, divisible by 4
    const int n4 = n / 4;            // 4194304 float4 elements
    const int block = 256;
    // Memory-bound streaming: cap grid at 8 blocks/CU (256 CU * 8 = 2048),
    // grid-stride the rest -> 8 float4 per thread, preamble fully amortized.
    const int grid = 2048;

    if (d_ws != nullptr && ws_size >= 16) {
        float* coef = (float*)d_ws;
        coeff_kernel<<<1, 64, 0, stream>>>(w, a, b, coef);
        stream_kernel<<<grid, block, 0, stream>>>(x, coef, out, n4);
    } else {
        fused_kernel<<<grid, block, 0, stream>>>(x, w, a, b, out, n4);
    }
}

// Round 2
// 117.190 us; speedup vs baseline: 1.0258x; 1.0258x over previous
//
#include <hip/hip_runtime.h>

// QuantumPINN: out = a*z + b, z = <psi| Z |psi>, psi = U(weights) RY(x)|0>.
// Algebraic collapse: out = K0 + K1*cos(x) + K2*sin(x), with K* derived from
// the 2x2 weight-only unitary (6 floats). Single fused launch:
//  - wave 0 of each block computes the (uniform) coefficients, broadcasts via LDS
//  - all threads stream float4, 2 trans + 3 fma per element (BW-bound: ~780
//    BW-cycles vs ~60 compute-cycles per wave-iteration)

struct cplx { float re, im; };

__device__ inline cplx cmul(cplx p, cplx q) {
    return cplx{p.re * q.re - p.im * q.im, p.re * q.im + p.im * q.re};
}
__device__ inline cplx cadd(cplx p, cplx q) { return cplx{p.re + q.re, p.im + q.im}; }

// Coefficients from the 6 weights. Fast __sincosf: ~600 VALU cycles, one wave/block.
__device__ inline void qpinn_coeffs(const float* __restrict__ w, float a, float b,
                                    float& K0, float& K1, float& K2) {
    cplx U00{1.f, 0.f}, U01{0.f, 0.f}, U10{0.f, 0.f}, U11{1.f, 0.f};
    #pragma unroll
    for (int l = 0; l < 2; ++l) {
        const float h0 = 0.5f * w[3 * l + 0];
        const float h1 = 0.5f * w[3 * l + 1];
        const float h2 = 0.5f * w[3 * l + 2];
        float c0, s0, c1, s1, c2, s2;
        __sincosf(h0, &s0, &c0);
        __sincosf(h1, &s1, &c1);
        __sincosf(h2, &s2, &c2);

        // RX = [[c0, -i s0], [-i s0, c0]]
        cplx X00{c0, 0.f}, X01{0.f, -s0}, X10{0.f, -s0}, X11{c0, 0.f};
        // RY = [[c1, -s1], [s1, c1]]
        cplx Y00{c1, 0.f}, Y01{-s1, 0.f}, Y10{s1, 0.f}, Y11{c1, 0.f};
        cplx A00 = cadd(cmul(Y00, X00), cmul(Y01, X10));
        cplx A01 = cadd(cmul(Y00, X01), cmul(Y01, X11));
        cplx A10 = cadd(cmul(Y10, X00), cmul(Y11, X10));
        cplx A11 = cadd(cmul(Y10, X01), cmul(Y11, X11));
        // RZ = diag(e^{-i h2}, e^{+i h2})
        cplx zm{c2, -s2}, zp{c2, s2};
        cplx L00 = cmul(zm, A00), L01 = cmul(zm, A01);
        cplx L10 = cmul(zp, A10), L11 = cmul(zp, A11);
        cplx n00 = cadd(cmul(L00, U00), cmul(L01, U10));
        cplx n01 = cadd(cmul(L00, U01), cmul(L01, U11));
        cplx n10 = cadd(cmul(L10, U00), cmul(L11, U10));
        cplx n11 = cadd(cmul(L10, U01), cmul(L11, U11));
        U00 = n00; U01 = n01; U10 = n10; U11 = n11;
    }
    const float A = (U00.re * U00.re + U00.im * U00.im) - (U10.re * U10.re + U10.im * U10.im);
    const float B = (U01.re * U01.re + U01.im * U01.im) - (U11.re * U11.re + U11.im * U11.im);
    const float C = 2.f * ((U00.re * U01.re + U00.im * U01.im) -
                           (U10.re * U11.re + U10.im * U11.im));
    K0 = fmaf(a, 0.5f * (A + B), b);
    K1 = a * 0.5f * (A - B);
    K2 = a * 0.5f * C;
}

__global__ __launch_bounds__(256) void qpinn_fused(
    const float* __restrict__ x, const float* __restrict__ w,
    const float* __restrict__ pa, const float* __restrict__ pb,
    float* __restrict__ out, int n4) {

    __shared__ float sc[3];
    if (threadIdx.x == 0) {
        float K0, K1, K2;
        qpinn_coeffs(w, pa[0], pb[0], K0, K1, K2);
        sc[0] = K0; sc[1] = K1; sc[2] = K2;
    }
    __syncthreads();
    const float K0 = sc[0];   // same-address LDS read -> broadcast, no conflict
    const float K1 = sc[1];
    const float K2 = sc[2];

    const float4* __restrict__ x4 = (const float4*)x;
    float4* __restrict__ o4 = (float4*)out;

    const int stride = gridDim.x * blockDim.x;
    for (int i = blockIdx.x * blockDim.x + threadIdx.x; i < n4; i += stride) {
        float4 v = x4[i];
        float4 r;
        float sx, cx;
        __sincosf(v.x, &sx, &cx); r.x = fmaf(K1, cx, fmaf(K2, sx, K0));
        __sincosf(v.y, &sx, &cx); r.y = fmaf(K1, cx, fmaf(K2, sx, K0));
        __sincosf(v.z, &sx, &cx); r.z = fmaf(K1, cx, fmaf(K2, sx, K0));
        __sincosf(v.w, &sx, &cx); r.w = fmaf(K1, cx, fmaf(K2, sx, K0));
        o4[i] = r;
    }
}

extern "C" void kernel_launch(void* const* d_in, const int* in_sizes, int n_in,
                              void* d_out, int out_size, void* d_ws, size_t ws_size,
                              hipStream_t stream) {
    const float* x = (const float*)d_in[0];
    const float* w = (const float*)d_in[1];   // [L=2, 3]
    const float* a = (const float*)d_in[2];
    const float* b = (const float*)d_in[3];
    float* out = (float*)d_out;

    const int n = in_sizes[0];       // 16777216, divisible by 4
    const int n4 = n / 4;            // 4194304 float4 elements
    const int block = 256;
    // Memory-bound streaming: 8 blocks/CU (256 CU * 8 = 2048) = 32 waves/CU
    // full occupancy; grid-stride -> 8 float4/thread, preamble amortized.
    const int grid = 2048;

    qpinn_fused<<<grid, block, 0, stream>>>(x, w, a, b, out, n4);
}

// Round 4
// 113.071 us; speedup vs baseline: 1.0632x; 1.0364x over previous
//
#include <hip/hip_runtime.h>

// QuantumPINN: out = a*z + b, z = <psi| Z |psi>, psi = U(weights) RY(x)|0>.
// Algebraic collapse: out = K0 + K1*cos(x) + K2*sin(x) = K0 + R*cos(x - phi).
// Single dispatch. Per element: fma (radians->revolutions + phase) -> v_cos_f32
// -> fma. 1 trans + 2 VALU per element, unroll-2 for MLP, NT stores.

// Native clang vector (HIP's float4 is a class; nontemporal builtin needs this).
typedef float f32x4 __attribute__((ext_vector_type(4)));

struct cplx { float re, im; };

__device__ inline cplx cmul(cplx p, cplx q) {
    return cplx{p.re * q.re - p.im * q.im, p.re * q.im + p.im * q.re};
}
__device__ inline cplx cadd(cplx p, cplx q) { return cplx{p.re + q.re, p.im + q.im}; }

// Accurate coefficient computation (runs on ONE thread per block; ~0.1us).
__device__ inline void qpinn_coeffs(const float* __restrict__ w, float a, float b,
                                    float& K0, float& R, float& mphirev) {
    cplx U00{1.f, 0.f}, U01{0.f, 0.f}, U10{0.f, 0.f}, U11{1.f, 0.f};
    #pragma unroll
    for (int l = 0; l < 2; ++l) {
        const float h0 = 0.5f * w[3 * l + 0];
        const float h1 = 0.5f * w[3 * l + 1];
        const float h2 = 0.5f * w[3 * l + 2];
        float c0, s0, c1, s1, c2, s2;
        sincosf(h0, &s0, &c0);
        sincosf(h1, &s1, &c1);
        sincosf(h2, &s2, &c2);

        cplx X00{c0, 0.f}, X01{0.f, -s0}, X10{0.f, -s0}, X11{c0, 0.f};
        cplx Y00{c1, 0.f}, Y01{-s1, 0.f}, Y10{s1, 0.f}, Y11{c1, 0.f};
        cplx A00 = cadd(cmul(Y00, X00), cmul(Y01, X10));
        cplx A01 = cadd(cmul(Y00, X01), cmul(Y01, X11));
        cplx A10 = cadd(cmul(Y10, X00), cmul(Y11, X10));
        cplx A11 = cadd(cmul(Y10, X01), cmul(Y11, X11));
        cplx zm{c2, -s2}, zp{c2, s2};
        cplx L00 = cmul(zm, A00), L01 = cmul(zm, A01);
        cplx L10 = cmul(zp, A10), L11 = cmul(zp, A11);
        cplx n00 = cadd(cmul(L00, U00), cmul(L01, U10));
        cplx n01 = cadd(cmul(L00, U01), cmul(L01, U11));
        cplx n10 = cadd(cmul(L10, U00), cmul(L11, U10));
        cplx n11 = cadd(cmul(L10, U01), cmul(L11, U11));
        U00 = n00; U01 = n01; U10 = n10; U11 = n11;
    }
    const float A = (U00.re * U00.re + U00.im * U00.im) - (U10.re * U10.re + U10.im * U10.im);
    const float B = (U01.re * U01.re + U01.im * U01.im) - (U11.re * U11.re + U11.im * U11.im);
    const float C = 2.f * ((U00.re * U01.re + U00.im * U01.im) -
                           (U10.re * U11.re + U10.im * U11.im));
    K0 = fmaf(a, 0.5f * (A + B), b);
    const float K1 = a * 0.5f * (A - B);
    const float K2 = a * 0.5f * C;
    R = sqrtf(K1 * K1 + K2 * K2);
    const float INV2PI = 0.15915494309189535f;
    mphirev = -atan2f(K2, K1) * INV2PI;   // phase in revolutions (v_cos_f32 units)
}

__device__ inline f32x4 qpinn_elem4(f32x4 v, float K0, float R, float mph) {
    const float INV2PI = 0.15915494309189535f;
    f32x4 r;
    // |x| < ~6 => |t| < 1 revolution, inside v_cos_f32's exact range.
    r.x = fmaf(R, __builtin_amdgcn_cosf(fmaf(v.x, INV2PI, mph)), K0);
    r.y = fmaf(R, __builtin_amdgcn_cosf(fmaf(v.y, INV2PI, mph)), K0);
    r.z = fmaf(R, __builtin_amdgcn_cosf(fmaf(v.z, INV2PI, mph)), K0);
    r.w = fmaf(R, __builtin_amdgcn_cosf(fmaf(v.w, INV2PI, mph)), K0);
    return r;
}

__global__ __launch_bounds__(256) void qpinn_fused(
    const float* __restrict__ x, const float* __restrict__ w,
    const float* __restrict__ pa, const float* __restrict__ pb,
    float* __restrict__ out, int n4) {

    __shared__ float sc[3];
    if (threadIdx.x == 0) {
        float K0, R, mph;
        qpinn_coeffs(w, pa[0], pb[0], K0, R, mph);
        sc[0] = K0; sc[1] = R; sc[2] = mph;
    }
    __syncthreads();
    const float K0 = sc[0];   // same-address LDS read -> broadcast
    const float R  = sc[1];
    const float mph = sc[2];

    const f32x4* __restrict__ x4 = (const f32x4*)x;
    f32x4* __restrict__ o4 = (f32x4*)out;

    const int stride = gridDim.x * blockDim.x;
    int i = blockIdx.x * blockDim.x + threadIdx.x;

    // Unroll-2: two independent 1KB/wave loads in flight per iteration (2x MLP).
    for (; i + stride < n4; i += 2 * stride) {
        const int j = i + stride;
        f32x4 v0 = x4[i];
        f32x4 v1 = x4[j];
        f32x4 r0 = qpinn_elem4(v0, K0, R, mph);
        f32x4 r1 = qpinn_elem4(v1, K0, R, mph);
        // NT stores: out is write-once, never re-read -> don't pollute L2/L3
        __builtin_nontemporal_store(r0, &o4[i]);
        __builtin_nontemporal_store(r1, &o4[j]);
    }
    if (i < n4) {
        f32x4 v0 = x4[i];
        f32x4 r0 = qpinn_elem4(v0, K0, R, mph);
        __builtin_nontemporal_store(r0, &o4[i]);
    }
}

extern "C" void kernel_launch(void* const* d_in, const int* in_sizes, int n_in,
                              void* d_out, int out_size, void* d_ws, size_t ws_size,
                              hipStream_t stream) {
    const float* x = (const float*)d_in[0];
    const float* w = (const float*)d_in[1];   // [L=2, 3]
    const float* a = (const float*)d_in[2];
    const float* b = (const float*)d_in[3];
    float* out = (float*)d_out;

    const int n = in_sizes[0];       // 16777216, divisible by 4
    const int n4 = n / 4;            // 4194304 float4 elements
    const int block = 256;
    // 8 blocks/CU (256 CU): 32 waves/CU full occupancy; 8 float4/thread.
    const int grid = 2048;

    qpinn_fused<<<grid, block, 0, stream>>>(x, w, a, b, out, n4);
}